// Round 10
// baseline (892.481 us; speedup 1.0000x reference)
//
#include <hip/hip_runtime.h>
#include <math.h>

#define HID    128
#define IN_CH  271
#define SEQ    281
#define NCLS   1854
#define BATCH  256
#define M_TOT  (SEQ * BATCH)          // 71936 = 562 * 128
#define KPAD0  288                    // 271 padded to 9*32
#define LROW   136                    // LDS row stride in shorts (b128 reads; R7 layout)

typedef __attribute__((ext_vector_type(8))) short short8;
typedef __attribute__((ext_vector_type(4))) float floatx4;

#define MFMA16(acc, a, b) acc = __builtin_amdgcn_mfma_f32_16x16x32_bf16((a), (b), (acc), 0, 0, 0)

__device__ __forceinline__ unsigned short f2bf(float f) {
    union { float f; unsigned u; } v; v.f = f;
    unsigned u = v.u;
    u += 0x7FFF + ((u >> 16) & 1);        // RNE
    return (unsigned short)(u >> 16);
}

__device__ __forceinline__ float fast_rcp(float x) {
    float r;
    asm("v_rcp_f32 %0, %1" : "=v"(r) : "v"(x));
    return r;
}
__device__ __forceinline__ float fast_sigmoid(float s) {
    return fast_rcp(1.f + __expf(-s));
}
// tanh(x) = 2/(1+e^{-2x}) - 1 ; exp limits (inf/0) give exactly -1/+1, branch-free
__device__ __forceinline__ float fast_tanh(float s) {
    float e = __expf(-2.f * s);
    return __builtin_fmaf(2.f, fast_rcp(1.f + e), -1.f);
}

// LDS-only barrier: waits ds-ops but does NOT drain vmcnt.
__device__ __forceinline__ void sync_lds() {
    asm volatile("s_waitcnt lgkmcnt(0)\n\ts_barrier" ::: "memory");
}

__device__ __forceinline__ short8 ldsA(const unsigned short* base, int l15, int kk, int quad) {
    return *(const short8*)(base + l15 * LROW + kk * 32 + quad * 8);
}

// ---------------------------------------------------------------------------
// Transpose+convert X: X[b][k][t] fp32 -> Abf[(b*281+t)*288 + k] bf16.
// ---------------------------------------------------------------------------
__global__ __launch_bounds__(256) void xt_kernel(
    const float* __restrict__ X, unsigned short* __restrict__ Abf)
{
    const int tb = blockIdx.x;            // 0..4, t-tile of 64
    const int b  = blockIdx.y;
    const int tid = threadIdx.x;
    const int t0 = tb * 64;
    const float* __restrict__ Xb = X + (size_t)b * (IN_CH * SEQ);

    __shared__ float Xl[32][65];

    for (int kc = 0; kc < KPAD0 / 32; ++kc) {
#pragma unroll
        for (int r = 0; r < 8; ++r) {
            int e = tid + 256 * r;
            int kk = e >> 6, tt = e & 63;
            int k = kc * 32 + kk, t = t0 + tt;
            Xl[kk][tt] = (k < IN_CH && t < SEQ) ? Xb[k * SEQ + t] : 0.f;
        }
        __syncthreads();
        {
            int tt = tid >> 2, part = tid & 3;
            int t = t0 + tt;
            if (t < SEQ) {
                union { unsigned short s[8]; uint4 v; } u;
#pragma unroll
                for (int i = 0; i < 8; ++i) u.s[i] = f2bf(Xl[part * 8 + i][tt]);
                *(uint4*)(Abf + ((size_t)b * SEQ + t) * KPAD0 + kc * 32 + part * 8) = u.v;
            }
        }
        __syncthreads();
    }
}

// ---------------------------------------------------------------------------
// Weight transpose+convert. grid (12, 32), blockIdx.y = n-slice of 4.
// blk 0..2 : Wt0 [n][288]        = W0g[k][n], k<271 (gemm B, layer0 x-part)
// blk 3..5 : Wh0 [g*128+n][128]  = W0g[271+k][n]     (gru, layer0 h-part)
// blk 6..8 : Wx1 [g*128+n][128]  = W1g[k][n]         (gru, layer1 x-part)
// blk 9..11: Wh1 [g*128+n][128]  = W1g[128+k][n]     (gru, layer1 h-part)
// ---------------------------------------------------------------------------
__global__ __launch_bounds__(256) void wt_kernel(
    const float* __restrict__ Wr0, const float* __restrict__ Wu0, const float* __restrict__ Wo0,
    const float* __restrict__ Wr1, const float* __restrict__ Wu1, const float* __restrict__ Wo1,
    unsigned short* __restrict__ Wt0, unsigned short* __restrict__ Wh0,
    unsigned short* __restrict__ Wx1, unsigned short* __restrict__ Wh1)
{
    const int blk  = blockIdx.x;
    const int kind = blk / 3, g = blk % 3;
    const int tid  = threadIdx.x;
    const int n0   = blockIdx.y * 4;

    const float* __restrict__ W =
        (kind <= 1) ? ((g == 0) ? Wr0 : (g == 1) ? Wu0 : Wo0)
                    : ((g == 0) ? Wr1 : (g == 1) ? Wu1 : Wo1);

    if (kind == 0) {
        unsigned short* __restrict__ out = Wt0 + (size_t)g * HID * KPAD0;
        for (int n = n0; n < n0 + 4; ++n)
            for (int k = tid; k < KPAD0; k += 256) {
                float v = (k < IN_CH) ? W[(size_t)k * HID + n] : 0.f;
                out[(size_t)n * KPAD0 + k] = f2bf(v);
            }
    } else {
        const int rbase = (kind == 1) ? IN_CH : (kind == 2) ? 0 : HID;
        unsigned short* __restrict__ out =
            ((kind == 1) ? Wh0 : (kind == 2) ? Wx1 : Wh1) + (size_t)g * HID * HID;
        for (int n = n0; n < n0 + 4; ++n)
            for (int k = tid; k < HID; k += 256)
                out[(size_t)n * HID + k] = f2bf(W[(size_t)(rbase + k) * HID + n]);
    }
}

// ---------------------------------------------------------------------------
// bf16 MFMA GEMM (layer-0 x-contributions only).
// Logical row m' = t*256 + b; tile m0 = blk*128 -> tt = m0>>8, b0m = m0&255.
// Output: XG[(tt*384 + g*128 + n)*256 + b]  (fp32), float4 stores.
// ---------------------------------------------------------------------------
__global__ __launch_bounds__(256) void gemm_xg(
    const unsigned short* __restrict__ A,
    const unsigned short* __restrict__ Wt,
    const float* __restrict__ br, const float* __restrict__ bu, const float* __restrict__ bo,
    float* __restrict__ XG)
{
    const int g = blockIdx.y;
    const float* __restrict__ bias = (g == 0) ? br : (g == 1) ? bu : bo;
    const unsigned short* __restrict__ B = Wt + (size_t)g * HID * KPAD0;

    __shared__ unsigned short As[128 * 40];
    __shared__ unsigned short Bs[128 * 40];

    const int tid   = threadIdx.x;
    const int lane  = tid & 63;
    const int wave  = tid >> 6;
    const int l15   = lane & 15;
    const int quad  = lane >> 4;
    const int mhalf = wave >> 1;
    const int nhalf = wave & 1;
    const int m0    = blockIdx.x * 128;
    const int tt    = m0 >> 8;
    const int b0m   = m0 & 255;

    floatx4 acc[4][4];
#pragma unroll
    for (int im = 0; im < 4; ++im)
#pragma unroll
        for (int in = 0; in < 4; ++in) acc[im][in] = (floatx4)0.f;

    const int r0 = tid >> 2, p0 = tid & 3;
    const int r1 = (tid + 256) >> 2, p1 = tid & 3;

    for (int kt = 0; kt < KPAD0 / 32; ++kt) {
        if (kt) __syncthreads();
        const int kb = kt * 32;
        uint4 va0 = *(const uint4*)(A + ((size_t)(b0m + r0) * SEQ + tt) * KPAD0 + kb + p0 * 8);
        uint4 va1 = *(const uint4*)(A + ((size_t)(b0m + r1) * SEQ + tt) * KPAD0 + kb + p1 * 8);
        uint4 vb0 = *(const uint4*)(B + (size_t)r0 * KPAD0 + kb + p0 * 8);
        uint4 vb1 = *(const uint4*)(B + (size_t)r1 * KPAD0 + kb + p1 * 8);
        *(uint4*)(As + r0 * 40 + p0 * 8) = va0;
        *(uint4*)(As + r1 * 40 + p1 * 8) = va1;
        *(uint4*)(Bs + r0 * 40 + p0 * 8) = vb0;
        *(uint4*)(Bs + r1 * 40 + p1 * 8) = vb1;
        __syncthreads();

        short8 af[4], bf[4];
#pragma unroll
        for (int im = 0; im < 4; ++im)
            af[im] = *(const short8*)(As + (mhalf * 64 + im * 16 + l15) * 40 + quad * 8);
#pragma unroll
        for (int in = 0; in < 4; ++in)
            bf[in] = *(const short8*)(Bs + (nhalf * 64 + in * 16 + l15) * 40 + quad * 8);
#pragma unroll
        for (int im = 0; im < 4; ++im)
#pragma unroll
            for (int in = 0; in < 4; ++in)
                MFMA16(acc[im][in], af[im], bf[in]);
    }

    float bv[4];
#pragma unroll
    for (int in = 0; in < 4; ++in) bv[in] = bias[nhalf * 64 + in * 16 + l15];
#pragma unroll
    for (int im = 0; im < 4; ++im) {
        const int bb = b0m + mhalf * 64 + im * 16 + quad * 4;
#pragma unroll
        for (int in = 0; in < 4; ++in) {
            const int n = nhalf * 64 + in * 16 + l15;
            float4 v = make_float4(acc[im][in][0] + bv[in], acc[im][in][1] + bv[in],
                                   acc[im][in][2] + bv[in], acc[im][in][3] + bv[in]);
            *(float4*)(XG + ((size_t)tt * 384 + g * HID + n) * BATCH + bb) = v;
        }
    }
}

// ---------------------------------------------------------------------------
// FUSED 2-layer GRU + classifier — R7's proven 4-phase structure.
// 16 batch rows/block, 16 blocks, 512 thr (8 waves, 2/SIMD). Wave w owns
// cols 16w..16w+15 of every gate of both layers; 36 weight B-fragments
// (144 AGPRs) hoisted as MFMA operands.
//   P1: L0 r,u + L1 r,u partials from h1(t-1)   [carry a1r,a1u to P3]
//   P2: L0 o + h0 update
//   P3: L1 x-contributions from h0(t); finish r1,u1
//   P4: L1 o + h1 update
// 4 LDS-only barriers/step.
// REGISTER DISCIPLINE (R9 lesson): arch-VGPR must stay <= ~110 so that
// vgpr+agpr <= 256/wave keeps 2 waves/SIMD. The 2-phase merge (R9) blew
// this (124+144=268 -> 1 wave/SIMD) and ran 33% slower. Do not merge phases;
// do not carry extra A-images across barriers.
// ---------------------------------------------------------------------------
__global__ __launch_bounds__(512, 1) void gru_fused(
    const unsigned short* __restrict__ Wh0,
    const unsigned short* __restrict__ Wx1,
    const unsigned short* __restrict__ Wh1,
    const float* __restrict__ XG,
    const float* __restrict__ br1, const float* __restrict__ bu1, const float* __restrict__ bo1,
    const float* __restrict__ Wfc, const float* __restrict__ bfc,
    float* __restrict__ out)
{
    const int b0   = blockIdx.x * 16;
    const int tid  = threadIdx.x;
    const int w    = tid >> 6;        // 0..7
    const int lane = tid & 63;
    const int l15  = lane & 15;
    const int quad = lane >> 4;
    const int c    = w * 16 + l15;    // this thread's column 0..127

    __shared__ __attribute__((aligned(16))) unsigned short Hbf0[16 * LROW];
    __shared__ __attribute__((aligned(16))) unsigned short Rbf0[16 * LROW];
    __shared__ __attribute__((aligned(16))) unsigned short Hbf1[16 * LROW];
    __shared__ __attribute__((aligned(16))) unsigned short Rbf1[16 * LROW];
    __shared__ float H1f[16][HID];

    // hoisted weight B-fragments: 9 (layer,gate) tiles x 4 k-steps
    short8 B0r[4], B0u[4], B0o[4], Bxr[4], Bxu[4], Bxo[4], B1r[4], B1u[4], B1o[4];
#pragma unroll
    for (int kk = 0; kk < 4; ++kk) {
        const size_t off = (size_t)(w * 16 + l15) * HID + kk * 32 + quad * 8;
        B0r[kk] = *(const short8*)(Wh0 + off);
        B0u[kk] = *(const short8*)(Wh0 + (size_t)128 * HID + off);
        B0o[kk] = *(const short8*)(Wh0 + (size_t)256 * HID + off);
        Bxr[kk] = *(const short8*)(Wx1 + off);
        Bxu[kk] = *(const short8*)(Wx1 + (size_t)128 * HID + off);
        Bxo[kk] = *(const short8*)(Wx1 + (size_t)256 * HID + off);
        B1r[kk] = *(const short8*)(Wh1 + off);
        B1u[kk] = *(const short8*)(Wh1 + (size_t)128 * HID + off);
        B1o[kk] = *(const short8*)(Wh1 + (size_t)256 * HID + off);
    }

    for (int idx = tid; idx < 16 * LROW; idx += 512) {
        Hbf0[idx] = 0; Rbf0[idx] = 0; Hbf1[idx] = 0; Rbf1[idx] = 0;
    }

    float h0c[4], h1c[4];
#pragma unroll
    for (int i = 0; i < 4; ++i) { h0c[i] = 0.f; h1c[i] = 0.f; }

    const float br1c = br1[c], bu1c = bu1[c], bo1c = bo1[c];

    const int XGSTEP = 384 * BATCH;
    const float* xgp = XG + (size_t)c * BATCH + b0 + quad * 4;   // t=0 row
    float4 xr4 = *(const float4*)(xgp);
    float4 xu4 = *(const float4*)(xgp + (size_t)128 * BATCH);
    float4 xo4 = *(const float4*)(xgp + (size_t)256 * BATCH);
    xgp += XGSTEP;
    __syncthreads();

    for (int t = 0; t < SEQ; ++t) {
        // prefetch xg(t+1) — uniform guard, lands during this step's compute
        float4 nr4, nu4, no4;
        const bool pf = (t + 1 < SEQ);
        if (pf) {
            nr4 = *(const float4*)(xgp);
            nu4 = *(const float4*)(xgp + (size_t)128 * BATCH);
            no4 = *(const float4*)(xgp + (size_t)256 * BATCH);
            xgp += XGSTEP;
        }

        // ---- P1: L0 r,u  +  L1 r,u partials from h1(t-1)
        floatx4 ar = (floatx4)0.f, au = (floatx4)0.f;
        floatx4 a1r = {br1c, br1c, br1c, br1c};
        floatx4 a1u = {bu1c, bu1c, bu1c, bu1c};
#pragma unroll
        for (int kk = 0; kk < 4; ++kk) {
            short8 a0 = ldsA(Hbf0, l15, kk, quad);
            short8 a1 = ldsA(Hbf1, l15, kk, quad);
            MFMA16(ar,  a0, B0r[kk]);
            MFMA16(au,  a0, B0u[kk]);
            MFMA16(a1r, a1, B1r[kk]);
            MFMA16(a1u, a1, B1u[kk]);
        }
        float ug0[4];
#pragma unroll
        for (int j = 0; j < 4; ++j) {
            float rg = fast_sigmoid(ar[j] + xr4[j]);
            ug0[j] = fast_sigmoid(au[j] + xu4[j]);
            Rbf0[(quad * 4 + j) * LROW + c] = f2bf(rg * h0c[j]);
        }
        sync_lds();

        // ---- P2: L0 o + h0 update
        floatx4 ao = (floatx4)0.f;
#pragma unroll
        for (int kk = 0; kk < 4; ++kk)
            MFMA16(ao, ldsA(Rbf0, l15, kk, quad), B0o[kk]);
#pragma unroll
        for (int j = 0; j < 4; ++j) {
            float og = fast_tanh(ao[j] + xo4[j]);
            h0c[j] = h0c[j] + ug0[j] * (og - h0c[j]);
            Hbf0[(quad * 4 + j) * LROW + c] = f2bf(h0c[j]);
        }
        sync_lds();

        // ---- P3: L1 x-contributions from h0(t); finish r1,u1
        floatx4 axo = {bo1c, bo1c, bo1c, bo1c};
#pragma unroll
        for (int kk = 0; kk < 4; ++kk) {
            short8 a0 = ldsA(Hbf0, l15, kk, quad);
            MFMA16(a1r, a0, Bxr[kk]);
            MFMA16(a1u, a0, Bxu[kk]);
            MFMA16(axo, a0, Bxo[kk]);
        }
        float ug1[4];
#pragma unroll
        for (int j = 0; j < 4; ++j) {
            float rg1 = fast_sigmoid(a1r[j]);
            ug1[j] = fast_sigmoid(a1u[j]);
            Rbf1[(quad * 4 + j) * LROW + c] = f2bf(rg1 * h1c[j]);
        }
        sync_lds();

        // ---- P4: L1 o + h1 update
#pragma unroll
        for (int kk = 0; kk < 4; ++kk)
            MFMA16(axo, ldsA(Rbf1, l15, kk, quad), B1o[kk]);
#pragma unroll
        for (int j = 0; j < 4; ++j) {
            float og1 = fast_tanh(axo[j]);
            h1c[j] = h1c[j] + ug1[j] * (og1 - h1c[j]);
            Hbf1[(quad * 4 + j) * LROW + c] = f2bf(h1c[j]);
        }
        if (pf) { xr4 = nr4; xu4 = nu4; xo4 = no4; }
        sync_lds();
    }

    // ---- fused classifier: out[b][cls] = bfc + h1[b][:] @ Wfc (register-light)
#pragma unroll
    for (int j = 0; j < 4; ++j) H1f[quad * 4 + j][c] = h1c[j];
    __syncthreads();

    const int bb = tid >> 5;          // 0..15
    const int cg = tid & 31;          // 0..31
    const float* __restrict__ hrow = &H1f[bb][0];
    float* __restrict__ orow = out + (size_t)(b0 + bb) * NCLS;

    for (int c0 = cg * 4; c0 + 4 <= NCLS; c0 += 128) {
        float4 a = *(const float4*)(bfc + c0);
#pragma unroll 4
        for (int k = 0; k < HID; ++k) {
            float hk = hrow[k];
            float4 wv = *(const float4*)(Wfc + (size_t)k * NCLS + c0);
            a.x += hk * wv.x; a.y += hk * wv.y; a.z += hk * wv.z; a.w += hk * wv.w;
        }
        *(float4*)(orow + c0) = a;
    }
    if (cg == 15) {                   // tail classes 1852, 1853
        for (int cc = 1852; cc < NCLS; ++cc) {
            float a = bfc[cc];
#pragma unroll 4
            for (int k = 0; k < HID; ++k)
                a += hrow[k] * Wfc[(size_t)k * NCLS + cc];
            orow[cc] = a;
        }
    }
}

// ---------------------------------------------------------------------------
extern "C" void kernel_launch(void* const* d_in, const int* in_sizes, int n_in,
                              void* d_out, int out_size, void* d_ws, size_t ws_size,
                              hipStream_t stream)
{
    const float* X   = (const float*)d_in[0];
    const float* Wr0 = (const float*)d_in[1];
    const float* br0 = (const float*)d_in[2];
    const float* Wu0 = (const float*)d_in[3];
    const float* bu0 = (const float*)d_in[4];
    const float* Wo0 = (const float*)d_in[5];
    const float* bo0 = (const float*)d_in[6];
    const float* Wr1 = (const float*)d_in[7];
    const float* br1 = (const float*)d_in[8];
    const float* Wu1 = (const float*)d_in[9];
    const float* bu1 = (const float*)d_in[10];
    const float* Wo1 = (const float*)d_in[11];
    const float* bo1 = (const float*)d_in[12];
    const float* Wfc = (const float*)d_in[13];
    const float* bfc = (const float*)d_in[14];
    float* out = (float*)d_out;

    // workspace:
    //   XG  fp32 [281*384*256]   110,493,696 B   ([t][chan][b])
    //   Abf bf16 [M_TOT*288]      41,435,136 B
    //   Wt0 bf16 [3*128*288]         221,184 B
    //   Wh0/Wx1/Wh1 bf16 [384*128]    98,304 B each
    char* ws = (char*)d_ws;
    float*          XG  = (float*)ws;
    unsigned short* Abf = (unsigned short*)(ws + (size_t)M_TOT * 384 * 4);
    unsigned short* Wt0 = (unsigned short*)(ws + (size_t)M_TOT * 384 * 4 + (size_t)M_TOT * KPAD0 * 2);
    unsigned short* Wh0 = Wt0 + (size_t)3 * HID * KPAD0;
    unsigned short* Wx1 = Wh0 + (size_t)384 * HID;
    unsigned short* Wh1 = Wx1 + (size_t)384 * HID;

    wt_kernel<<<dim3(12, 32), 256, 0, stream>>>(Wr0, Wu0, Wo0, Wr1, Wu1, Wo1,
                                                Wt0, Wh0, Wx1, Wh1);
    xt_kernel<<<dim3(5, BATCH), 256, 0, stream>>>(X, Abf);
    gemm_xg  <<<dim3(M_TOT / 128, 3), 256, 0, stream>>>(Abf, Wt0, br0, bu0, bo0, XG);
    gru_fused<<<dim3(16), 512, 0, stream>>>(Wh0, Wx1, Wh1, XG, br1, bu1, bo1,
                                            Wfc, bfc, out);
}

// Round 11
// 732.161 us; speedup vs baseline: 1.2190x; 1.2190x over previous
//
#include <hip/hip_runtime.h>
#include <math.h>

#define HID    128
#define IN_CH  271
#define SEQ    281
#define NCLS   1854
#define BATCH  256
#define M_TOT  (SEQ * BATCH)          // 71936 = 562 * 128
#define KPAD0  288                    // 271 padded to 9*32

typedef __attribute__((ext_vector_type(8))) short short8;
typedef __attribute__((ext_vector_type(4))) float floatx4;

#define MFMA16(acc, a, b) acc = __builtin_amdgcn_mfma_f32_16x16x32_bf16((a), (b), (acc), 0, 0, 0)

__device__ __forceinline__ unsigned short f2bf(float f) {
    union { float f; unsigned u; } v; v.f = f;
    unsigned u = v.u;
    u += 0x7FFF + ((u >> 16) & 1);        // RNE
    return (unsigned short)(u >> 16);
}

__device__ __forceinline__ float fast_rcp(float x) {
    float r;
    asm("v_rcp_f32 %0, %1" : "=v"(r) : "v"(x));
    return r;
}
__device__ __forceinline__ float fast_sigmoid(float s) {
    return fast_rcp(1.f + __expf(-s));
}
// tanh(x) = 2/(1+e^{-2x}) - 1 ; exp limits (inf/0) give exactly -1/+1, branch-free
__device__ __forceinline__ float fast_tanh(float s) {
    float e = __expf(-2.f * s);
    return __builtin_fmaf(2.f, fast_rcp(1.f + e), -1.f);
}

// LDS-only barrier: waits ds-ops but does NOT drain vmcnt.
__device__ __forceinline__ void sync_lds() {
    asm volatile("s_waitcnt lgkmcnt(0)\n\ts_barrier" ::: "memory");
}

// ---------------------------------------------------------------------------
// Swizzled LDS image layout (16 rows x 128 bf16, row stride 128 shorts):
//   element (row, k) lives at  row*128 + ((( k>>3 ) ^ (row&7)) << 3) + (k&7)
// b128 A-frag read (lane l15=row, chunk 4kk+quad): lanes spread over all 8
// chunk-slots -> 2 lanes/bank (free) instead of 16 dwords/bank (2x pipe).
// ---------------------------------------------------------------------------
__device__ __forceinline__ short8 ldsA_sw(const unsigned short* base, int l15, int kk, int quad) {
    const int chunk = (4 * kk + quad) ^ (l15 & 7);
    return *(const short8*)(base + l15 * 128 + (chunk << 3));
}
__device__ __forceinline__ int sw_idx(int row, int c) {
    return row * 128 + ((((c >> 3) ^ (row & 7)) << 3) | (c & 7));
}

// ---------------------------------------------------------------------------
// Transpose+convert X: X[b][k][t] fp32 -> Abf[(b*281+t)*288 + k] bf16.
// ---------------------------------------------------------------------------
__global__ __launch_bounds__(256) void xt_kernel(
    const float* __restrict__ X, unsigned short* __restrict__ Abf)
{
    const int tb = blockIdx.x;            // 0..4, t-tile of 64
    const int b  = blockIdx.y;
    const int tid = threadIdx.x;
    const int t0 = tb * 64;
    const float* __restrict__ Xb = X + (size_t)b * (IN_CH * SEQ);

    __shared__ float Xl[32][65];

    for (int kc = 0; kc < KPAD0 / 32; ++kc) {
#pragma unroll
        for (int r = 0; r < 8; ++r) {
            int e = tid + 256 * r;
            int kk = e >> 6, tt = e & 63;
            int k = kc * 32 + kk, t = t0 + tt;
            Xl[kk][tt] = (k < IN_CH && t < SEQ) ? Xb[k * SEQ + t] : 0.f;
        }
        __syncthreads();
        {
            int tt = tid >> 2, part = tid & 3;
            int t = t0 + tt;
            if (t < SEQ) {
                union { unsigned short s[8]; uint4 v; } u;
#pragma unroll
                for (int i = 0; i < 8; ++i) u.s[i] = f2bf(Xl[part * 8 + i][tt]);
                *(uint4*)(Abf + ((size_t)b * SEQ + t) * KPAD0 + kc * 32 + part * 8) = u.v;
            }
        }
        __syncthreads();
    }
}

// ---------------------------------------------------------------------------
// Weight transpose+convert. grid (12, 32), blockIdx.y = n-slice of 4.
// blk 0..2 : Wt0 [n][288]        = W0g[k][n], k<271 (gemm B, layer0 x-part)
// blk 3..5 : Wh0 [g*128+n][128]  = W0g[271+k][n]     (gru, layer0 h-part)
// blk 6..8 : Wx1 [g*128+n][128]  = W1g[k][n]         (gru, layer1 x-part)
// blk 9..11: Wh1 [g*128+n][128]  = W1g[128+k][n]     (gru, layer1 h-part)
// ---------------------------------------------------------------------------
__global__ __launch_bounds__(256) void wt_kernel(
    const float* __restrict__ Wr0, const float* __restrict__ Wu0, const float* __restrict__ Wo0,
    const float* __restrict__ Wr1, const float* __restrict__ Wu1, const float* __restrict__ Wo1,
    unsigned short* __restrict__ Wt0, unsigned short* __restrict__ Wh0,
    unsigned short* __restrict__ Wx1, unsigned short* __restrict__ Wh1)
{
    const int blk  = blockIdx.x;
    const int kind = blk / 3, g = blk % 3;
    const int tid  = threadIdx.x;
    const int n0   = blockIdx.y * 4;

    const float* __restrict__ W =
        (kind <= 1) ? ((g == 0) ? Wr0 : (g == 1) ? Wu0 : Wo0)
                    : ((g == 0) ? Wr1 : (g == 1) ? Wu1 : Wo1);

    if (kind == 0) {
        unsigned short* __restrict__ out = Wt0 + (size_t)g * HID * KPAD0;
        for (int n = n0; n < n0 + 4; ++n)
            for (int k = tid; k < KPAD0; k += 256) {
                float v = (k < IN_CH) ? W[(size_t)k * HID + n] : 0.f;
                out[(size_t)n * KPAD0 + k] = f2bf(v);
            }
    } else {
        const int rbase = (kind == 1) ? IN_CH : (kind == 2) ? 0 : HID;
        unsigned short* __restrict__ out =
            ((kind == 1) ? Wh0 : (kind == 2) ? Wx1 : Wh1) + (size_t)g * HID * HID;
        for (int n = n0; n < n0 + 4; ++n)
            for (int k = tid; k < HID; k += 256)
                out[(size_t)n * HID + k] = f2bf(W[(size_t)(rbase + k) * HID + n]);
    }
}

// ---------------------------------------------------------------------------
// bf16 MFMA GEMM (layer-0 x-contributions only).
// Logical row m' = t*256 + b; tile m0 = blk*128 -> tt = m0>>8, b0m = m0&255.
// Output: XG[(tt*384 + g*128 + n)*256 + b]  (fp32), float4 stores.
// ---------------------------------------------------------------------------
__global__ __launch_bounds__(256) void gemm_xg(
    const unsigned short* __restrict__ A,
    const unsigned short* __restrict__ Wt,
    const float* __restrict__ br, const float* __restrict__ bu, const float* __restrict__ bo,
    float* __restrict__ XG)
{
    const int g = blockIdx.y;
    const float* __restrict__ bias = (g == 0) ? br : (g == 1) ? bu : bo;
    const unsigned short* __restrict__ B = Wt + (size_t)g * HID * KPAD0;

    __shared__ unsigned short As[128 * 40];
    __shared__ unsigned short Bs[128 * 40];

    const int tid   = threadIdx.x;
    const int lane  = tid & 63;
    const int wave  = tid >> 6;
    const int l15   = lane & 15;
    const int quad  = lane >> 4;
    const int mhalf = wave >> 1;
    const int nhalf = wave & 1;
    const int m0    = blockIdx.x * 128;
    const int tt    = m0 >> 8;
    const int b0m   = m0 & 255;

    floatx4 acc[4][4];
#pragma unroll
    for (int im = 0; im < 4; ++im)
#pragma unroll
        for (int in = 0; in < 4; ++in) acc[im][in] = (floatx4)0.f;

    const int r0 = tid >> 2, p0 = tid & 3;
    const int r1 = (tid + 256) >> 2, p1 = tid & 3;

    for (int kt = 0; kt < KPAD0 / 32; ++kt) {
        if (kt) __syncthreads();
        const int kb = kt * 32;
        uint4 va0 = *(const uint4*)(A + ((size_t)(b0m + r0) * SEQ + tt) * KPAD0 + kb + p0 * 8);
        uint4 va1 = *(const uint4*)(A + ((size_t)(b0m + r1) * SEQ + tt) * KPAD0 + kb + p1 * 8);
        uint4 vb0 = *(const uint4*)(B + (size_t)r0 * KPAD0 + kb + p0 * 8);
        uint4 vb1 = *(const uint4*)(B + (size_t)r1 * KPAD0 + kb + p1 * 8);
        *(uint4*)(As + r0 * 40 + p0 * 8) = va0;
        *(uint4*)(As + r1 * 40 + p1 * 8) = va1;
        *(uint4*)(Bs + r0 * 40 + p0 * 8) = vb0;
        *(uint4*)(Bs + r1 * 40 + p1 * 8) = vb1;
        __syncthreads();

        short8 af[4], bf[4];
#pragma unroll
        for (int im = 0; im < 4; ++im)
            af[im] = *(const short8*)(As + (mhalf * 64 + im * 16 + l15) * 40 + quad * 8);
#pragma unroll
        for (int in = 0; in < 4; ++in)
            bf[in] = *(const short8*)(Bs + (nhalf * 64 + in * 16 + l15) * 40 + quad * 8);
#pragma unroll
        for (int im = 0; im < 4; ++im)
#pragma unroll
            for (int in = 0; in < 4; ++in)
                MFMA16(acc[im][in], af[im], bf[in]);
    }

    float bv[4];
#pragma unroll
    for (int in = 0; in < 4; ++in) bv[in] = bias[nhalf * 64 + in * 16 + l15];
#pragma unroll
    for (int im = 0; im < 4; ++im) {
        const int bb = b0m + mhalf * 64 + im * 16 + quad * 4;
#pragma unroll
        for (int in = 0; in < 4; ++in) {
            const int n = nhalf * 64 + in * 16 + l15;
            float4 v = make_float4(acc[im][in][0] + bv[in], acc[im][in][1] + bv[in],
                                   acc[im][in][2] + bv[in], acc[im][in][3] + bv[in]);
            *(float4*)(XG + ((size_t)tt * 384 + g * HID + n) * BATCH + bb) = v;
        }
    }
}

// ---------------------------------------------------------------------------
// FUSED 2-layer GRU — R7's proven 4-phase structure + XOR-swizzled LDS.
// 16 batch rows/block, 16 blocks, 512 thr (8 waves, 2/SIMD). Wave w owns
// cols 16w..16w+15 of every gate of both layers; 36 weight B-fragments
// (144 AGPRs) hoisted as MFMA operands.
//   P1: L0 r,u + L1 r,u partials from h1(t-1)   [carry a1r,a1u to P3]
//   P2: L0 o + h0 update
//   P3: L1 x-contributions from h0(t); finish r1,u1
//   P4: L1 o + h1 update
// 4 LDS-only barriers/step. NO classifier tail (R8/R10: +12 arch VGPR ->
// 264>256 unified budget -> 1 wave/SIMD -> +200 µs. Keep arch <= 112!).
// ---------------------------------------------------------------------------
__global__ __launch_bounds__(512, 1) void gru_fused(
    const unsigned short* __restrict__ Wh0,
    const unsigned short* __restrict__ Wx1,
    const unsigned short* __restrict__ Wh1,
    const float* __restrict__ XG,
    const float* __restrict__ br1, const float* __restrict__ bu1, const float* __restrict__ bo1,
    float* __restrict__ H1fin)
{
    const int b0   = blockIdx.x * 16;
    const int tid  = threadIdx.x;
    const int w    = tid >> 6;        // 0..7
    const int lane = tid & 63;
    const int l15  = lane & 15;
    const int quad = lane >> 4;
    const int c    = w * 16 + l15;    // this thread's column 0..127

    __shared__ __attribute__((aligned(16))) unsigned short Hbf0[16 * 128];
    __shared__ __attribute__((aligned(16))) unsigned short Rbf0[16 * 128];
    __shared__ __attribute__((aligned(16))) unsigned short Hbf1[16 * 128];
    __shared__ __attribute__((aligned(16))) unsigned short Rbf1[16 * 128];

    // hoisted weight B-fragments: 9 (layer,gate) tiles x 4 k-steps
    short8 B0r[4], B0u[4], B0o[4], Bxr[4], Bxu[4], Bxo[4], B1r[4], B1u[4], B1o[4];
#pragma unroll
    for (int kk = 0; kk < 4; ++kk) {
        const size_t off = (size_t)(w * 16 + l15) * HID + kk * 32 + quad * 8;
        B0r[kk] = *(const short8*)(Wh0 + off);
        B0u[kk] = *(const short8*)(Wh0 + (size_t)128 * HID + off);
        B0o[kk] = *(const short8*)(Wh0 + (size_t)256 * HID + off);
        Bxr[kk] = *(const short8*)(Wx1 + off);
        Bxu[kk] = *(const short8*)(Wx1 + (size_t)128 * HID + off);
        Bxo[kk] = *(const short8*)(Wx1 + (size_t)256 * HID + off);
        B1r[kk] = *(const short8*)(Wh1 + off);
        B1u[kk] = *(const short8*)(Wh1 + (size_t)128 * HID + off);
        B1o[kk] = *(const short8*)(Wh1 + (size_t)256 * HID + off);
    }

    for (int idx = tid; idx < 16 * 128; idx += 512) {
        Hbf0[idx] = 0; Rbf0[idx] = 0; Hbf1[idx] = 0; Rbf1[idx] = 0;
    }

    float h0c[4], h1c[4];
#pragma unroll
    for (int i = 0; i < 4; ++i) { h0c[i] = 0.f; h1c[i] = 0.f; }

    const float br1c = br1[c], bu1c = bu1[c], bo1c = bo1[c];

    // swizzled store indices for this thread's 4 rows (col c fixed)
    int sidx[4];
#pragma unroll
    for (int j = 0; j < 4; ++j) sidx[j] = sw_idx(quad * 4 + j, c);

    const int XGSTEP = 384 * BATCH;
    const float* xgp = XG + (size_t)c * BATCH + b0 + quad * 4;   // t=0 row
    float4 xr4 = *(const float4*)(xgp);
    float4 xu4 = *(const float4*)(xgp + (size_t)128 * BATCH);
    float4 xo4 = *(const float4*)(xgp + (size_t)256 * BATCH);
    xgp += XGSTEP;
    __syncthreads();

    for (int t = 0; t < SEQ; ++t) {
        // prefetch xg(t+1) — lands during this step's compute
        float4 nr4, nu4, no4;
        const bool pf = (t + 1 < SEQ);
        if (pf) {
            nr4 = *(const float4*)(xgp);
            nu4 = *(const float4*)(xgp + (size_t)128 * BATCH);
            no4 = *(const float4*)(xgp + (size_t)256 * BATCH);
            xgp += XGSTEP;
        }

        // ---- P1: L0 r,u  +  L1 r,u partials from h1(t-1)
        floatx4 ar = (floatx4)0.f, au = (floatx4)0.f;
        floatx4 a1r = (floatx4)0.f, a1u = (floatx4)0.f;
#pragma unroll
        for (int kk = 0; kk < 4; ++kk) {
            short8 a0 = ldsA_sw(Hbf0, l15, kk, quad);
            short8 a1 = ldsA_sw(Hbf1, l15, kk, quad);
            MFMA16(ar,  a0, B0r[kk]);
            MFMA16(au,  a0, B0u[kk]);
            MFMA16(a1r, a1, B1r[kk]);
            MFMA16(a1u, a1, B1u[kk]);
        }
        float ug0[4];
#pragma unroll
        for (int j = 0; j < 4; ++j) {
            float rg = fast_sigmoid(ar[j] + xr4[j]);
            ug0[j] = fast_sigmoid(au[j] + xu4[j]);
            Rbf0[sidx[j]] = f2bf(rg * h0c[j]);
        }
        sync_lds();

        // ---- P2: L0 o + h0 update
        floatx4 ao = (floatx4)0.f;
#pragma unroll
        for (int kk = 0; kk < 4; ++kk)
            MFMA16(ao, ldsA_sw(Rbf0, l15, kk, quad), B0o[kk]);
#pragma unroll
        for (int j = 0; j < 4; ++j) {
            float og = fast_tanh(ao[j] + xo4[j]);
            h0c[j] = h0c[j] + ug0[j] * (og - h0c[j]);
            Hbf0[sidx[j]] = f2bf(h0c[j]);
        }
        sync_lds();

        // ---- P3: L1 x-contributions from h0(t); finish r1,u1
        floatx4 axo = (floatx4)0.f;
#pragma unroll
        for (int kk = 0; kk < 4; ++kk) {
            short8 a0 = ldsA_sw(Hbf0, l15, kk, quad);
            MFMA16(a1r, a0, Bxr[kk]);
            MFMA16(a1u, a0, Bxu[kk]);
            MFMA16(axo, a0, Bxo[kk]);
        }
        float ug1[4];
#pragma unroll
        for (int j = 0; j < 4; ++j) {
            float rg1 = fast_sigmoid(a1r[j] + br1c);
            ug1[j] = fast_sigmoid(a1u[j] + bu1c);
            Rbf1[sidx[j]] = f2bf(rg1 * h1c[j]);
        }
        sync_lds();

        // ---- P4: L1 o + h1 update
#pragma unroll
        for (int kk = 0; kk < 4; ++kk)
            MFMA16(axo, ldsA_sw(Rbf1, l15, kk, quad), B1o[kk]);
#pragma unroll
        for (int j = 0; j < 4; ++j) {
            float og1 = fast_tanh(axo[j] + bo1c);
            h1c[j] = h1c[j] + ug1[j] * (og1 - h1c[j]);
            Hbf1[sidx[j]] = f2bf(h1c[j]);
        }
        if (pf) { xr4 = nr4; xu4 = nu4; xo4 = no4; }
        sync_lds();
    }

#pragma unroll
    for (int j = 0; j < 4; ++j)
        H1fin[(size_t)(b0 + quad * 4 + j) * HID + c] = h1c[j];
}

// ---------------------------------------------------------------------------
// Classifier: out[b][c] = bfc[c] + sum_k H1[b][k] * Wfc[k][c]
// ---------------------------------------------------------------------------
__global__ __launch_bounds__(256) void cls_kernel(
    const float* __restrict__ H1, const float* __restrict__ Wfc,
    const float* __restrict__ bfc, float* __restrict__ out)
{
    const int b = blockIdx.x;
    const int tid = threadIdx.x;
    __shared__ float h[HID];
    if (tid < HID) h[tid] = H1[(size_t)b * HID + tid];
    __syncthreads();
    for (int c = tid; c < NCLS; c += 256) {
        float a = bfc[c];
#pragma unroll 8
        for (int k = 0; k < HID; ++k)
            a += h[k] * Wfc[(size_t)k * NCLS + c];
        out[(size_t)b * NCLS + c] = a;
    }
}

// ---------------------------------------------------------------------------
extern "C" void kernel_launch(void* const* d_in, const int* in_sizes, int n_in,
                              void* d_out, int out_size, void* d_ws, size_t ws_size,
                              hipStream_t stream)
{
    const float* X   = (const float*)d_in[0];
    const float* Wr0 = (const float*)d_in[1];
    const float* br0 = (const float*)d_in[2];
    const float* Wu0 = (const float*)d_in[3];
    const float* bu0 = (const float*)d_in[4];
    const float* Wo0 = (const float*)d_in[5];
    const float* bo0 = (const float*)d_in[6];
    const float* Wr1 = (const float*)d_in[7];
    const float* br1 = (const float*)d_in[8];
    const float* Wu1 = (const float*)d_in[9];
    const float* bu1 = (const float*)d_in[10];
    const float* Wo1 = (const float*)d_in[11];
    const float* bo1 = (const float*)d_in[12];
    const float* Wfc = (const float*)d_in[13];
    const float* bfc = (const float*)d_in[14];
    float* out = (float*)d_out;

    // workspace:
    //   XG  fp32 [281*384*256]   110,493,696 B   ([t][chan][b])
    //   Abf bf16 [M_TOT*288]      41,435,136 B   (H1fin aliases: dead after gemm)
    //   Wt0 bf16 [3*128*288]         221,184 B
    //   Wh0/Wx1/Wh1 bf16 [384*128]    98,304 B each
    char* ws = (char*)d_ws;
    float*          XG    = (float*)ws;
    unsigned short* Abf   = (unsigned short*)(ws + (size_t)M_TOT * 384 * 4);
    float*          H1fin = (float*)Abf;        // alias: Abf dead after gemm_xg
    unsigned short* Wt0   = (unsigned short*)(ws + (size_t)M_TOT * 384 * 4 + (size_t)M_TOT * KPAD0 * 2);
    unsigned short* Wh0   = Wt0 + (size_t)3 * HID * KPAD0;
    unsigned short* Wx1   = Wh0 + (size_t)384 * HID;
    unsigned short* Wh1   = Wx1 + (size_t)384 * HID;

    wt_kernel<<<dim3(12, 32), 256, 0, stream>>>(Wr0, Wu0, Wo0, Wr1, Wu1, Wo1,
                                                Wt0, Wh0, Wx1, Wh1);
    xt_kernel<<<dim3(5, BATCH), 256, 0, stream>>>(X, Abf);
    gemm_xg  <<<dim3(M_TOT / 128, 3), 256, 0, stream>>>(Abf, Wt0, br0, bu0, bo0, XG);
    gru_fused<<<dim3(16), 512, 0, stream>>>(Wh0, Wx1, Wh1, XG, br1, bu1, bo1, H1fin);
    cls_kernel<<<dim3(BATCH), 256, 0, stream>>>(H1fin, Wfc, bfc, out);
}